// Round 8
// baseline (273.357 us; speedup 1.0000x reference)
//
#include <hip/hip_runtime.h>
#include <hip/hip_bf16.h>

#define NN 20000
#define NE 320000
#define NCH 17        // 16 conv slots + 1 fc slot, K chunks of 32
#define SROW 561      // per-node-partial LDS row stride (floats): 17*33, odd
#define FCOFF 528     // 16*33: fc slot base within row

typedef __attribute__((ext_vector_type(8))) short short8;
typedef __attribute__((ext_vector_type(4))) float f32x4;

__device__ __forceinline__ unsigned short f2bf(float v) {
    unsigned u = __float_as_uint(v);
    unsigned r = (u + 0x7fffu + ((u >> 16) & 1u)) >> 16;
    return (unsigned short)r;
}
__device__ __forceinline__ float bf2f(unsigned short s) {
    return __uint_as_float(((unsigned)s) << 16);
}
__device__ __forceinline__ unsigned short f2h(float v) {
    union { _Float16 h; unsigned short u; } cv;
    cv.h = (_Float16)v;
    return cv.u;
}
__device__ __forceinline__ float h2f(unsigned short u) {
    union { unsigned short u; _Float16 h; } cv;
    cv.u = u;
    return (float)cv.h;
}

struct WPtrs { const float* cw[4]; const float* fw[4]; };

// ---- fused build: [0,1250) edge histogram; [1250,1563) cast feat->bf16 x0;
//      [1563,1597) build W2frag (pre-swizzled MFMA B-fragments, all 4 layers)
__global__ __launch_bounds__(256) void histprep_kernel(const int* __restrict__ ei,
                                                       int* __restrict__ counts,
                                                       WPtrs wp,
                                                       const float* __restrict__ feat,
                                                       unsigned short* __restrict__ x0,
                                                       unsigned short* __restrict__ w2frag) {
    int b = blockIdx.x, t = threadIdx.x;
    if (b < 1250) {
        int e = b * 256 + t;                     // 1250*256 == NE exactly
        atomicAdd(&counts[ei[e]], 1);
    } else if (b < 1563) {
        int idx = (b - 1250) * 256 + t;          // 80000 groups of 8 elems
        if (idx < 80000) {
            const float4* fsrc = (const float4*)(feat + (size_t)idx * 8);
            float4 a = fsrc[0], c = fsrc[1];
            short8 o;
            o[0] = (short)f2bf(a.x); o[1] = (short)f2bf(a.y);
            o[2] = (short)f2bf(a.z); o[3] = (short)f2bf(a.w);
            o[4] = (short)f2bf(c.x); o[5] = (short)f2bf(c.y);
            o[6] = (short)f2bf(c.z); o[7] = (short)f2bf(c.w);
            *(short8*)(x0 + (size_t)idx * 8) = o;
        }
    } else {
        int id2 = (b - 1563) * 256 + t;          // 4l * 2tile * 17c * 64lane = 8704
        if (id2 < 8704) {
            int lane = id2 & 63;
            int c = (id2 >> 6) % NCH;
            int lt = id2 / (NCH * 64);
            int l = lt >> 1, tt = lt & 1;
            int kb = (lane >> 4) * 8;
            int col = tt * 16 + (lane & 15);
            short8 o;
#pragma unroll
            for (int i = 0; i < 8; i++) {
                int k = c * 32 + kb + i;
                float v = (k < 512) ? wp.cw[l][(size_t)k * 32 + col]
                                    : wp.fw[l][(size_t)(k - 512) * 32 + col];
                o[i] = (short)f2bf(v);
            }
            *(short8*)(w2frag + (size_t)id2 * 8) = o;
        }
    }
}

// ---- CSR build: single-block scan, 20 elements/thread, fully unrolled
__global__ __launch_bounds__(1024) void scan_kernel(const int* __restrict__ counts,
                                                    int* __restrict__ rowst,
                                                    int* __restrict__ cursor) {
    __shared__ int s[1024];
    int t = threadIdx.x;
    int base = t * 20;
    int v[20];
    int sum = 0;
#pragma unroll
    for (int i = 0; i < 20; i++) {
        int idx = base + i;
        v[i] = (idx < NN) ? counts[idx] : 0;
        sum += v[i];
    }
    s[t] = sum;
    __syncthreads();
#pragma unroll
    for (int off = 1; off < 1024; off <<= 1) {
        int add = (t >= off) ? s[t - off] : 0;
        __syncthreads();
        s[t] += add;
        __syncthreads();
    }
    int run = s[t] - sum;
    if (t == 0) rowst[0] = 0;
#pragma unroll
    for (int i = 0; i < 20; i++) {
        int idx = base + i;
        if (idx < NN) {
            cursor[idx] = run;
            rowst[idx + 1] = run + v[i];
        }
        run += v[i];
    }
}

// ---- CSR fill + edge basis precompute (layer-invariant)
// ejb[p] = j | bb<<16 ; ew[p] = { f16x2 w(dx=0; dy0 lo, dy1 hi), f16x2 w(dx=1) }
__global__ __launch_bounds__(256) void fill_kernel(const int* __restrict__ ei,
                                                   const int* __restrict__ ej,
                                                   const float* __restrict__ attr,
                                                   int* __restrict__ cursor,
                                                   unsigned* __restrict__ ejb,
                                                   uint2* __restrict__ ew) {
    int e = blockIdx.x * 256 + threadIdx.x;
    if (e >= NE) return;
    int i = ei[e], j = ej[e];
    int p = atomicAdd(&cursor[i], 1);
    float2 a = ((const float2*)attr)[e];
    float d0 = fminf(fmaxf(a.x, -1.f), 1.f);
    float d1 = fminf(fmaxf(a.y, -1.f), 1.f);
    float tx = (d0 + 1.f) * 1.5f;
    float ty = (d1 + 1.f) * 1.5f;
    int ix = min(2, max(0, (int)floorf(tx)));
    int iy = min(2, max(0, (int)floorf(ty)));
    float ux = tx - (float)ix;
    float uy = ty - (float)iy;
    float m = (i != j) ? 1.f : 0.f;   // centerIgnore
    uint2 w;
    w.x = (unsigned)f2h((1.f - ux) * (1.f - uy) * m)
        | ((unsigned)f2h((1.f - ux) * uy * m) << 16);
    w.y = (unsigned)f2h(ux * (1.f - uy) * m)
        | ((unsigned)f2h(ux * uy * m) << 16);
    ejb[p] = (unsigned)j | ((unsigned)(ix * 4 + iy) << 16);
    ew[p] = w;
}

// ---- fused layer: 4 nodes/block, 4 waves/node (stride-4 interleaved edge walk),
// each wave scatters into its OWN partial LDS row (16 rows = one MFMA A-tile).
// Phase B: waves 0,1 do ans = S . W2; node lg's result = sum of acc[0..3]
// (D-rows 4lg..4lg+3 are node lg's four partials). +bias/residual/relu.
__global__ __launch_bounds__(1024, 4) void fused_kernel(const unsigned short* __restrict__ xin,
                                                        unsigned short* __restrict__ xout,
                                                        const unsigned* __restrict__ ejb,
                                                        const uint2* __restrict__ ew,
                                                        const int* __restrict__ rowst,
                                                        const unsigned short* __restrict__ w2frag,
                                                        const float* __restrict__ bias,
                                                        float* __restrict__ ansbuf,
                                                        float* __restrict__ outf,
                                                        int mode) {
    __shared__ float s[16][SROW];
    int tid = threadIdx.x;
    int wv = tid >> 6, lane = tid & 63;
    for (int i = tid; i < 16 * SROW; i += 1024) ((float*)s)[i] = 0.f;
    __syncthreads();

    int fp = lane & 15;
    int g = lane >> 4;
    int dy = g & 1, dx = g >> 1;
    int soff = dx * 4 + dy;            // slot offset: {0,1,4,5}
    int nodeb = wv >> 2;               // node within block
    int h = wv & 3;                    // quarter id
    int node = blockIdx.x * 4 + nodeb;
    int r0 = rowst[node], r1 = rowst[node + 1];
    float* srow = s[wv];               // this wave's partial row

    int q = r0 + h;
    if (q < r1) {
        const unsigned* ewu = (const unsigned*)ew;
        int last = r1 - 1;
        // 2-deep pipeline: meta 2 iters ahead, x 1 iter ahead
        unsigned mA = ejb[q];
        unsigned wA = ewu[(size_t)q * 2 + dx];
        int qB = min(q + 4, last);
        unsigned mB = ejb[qB];
        unsigned wB = ewu[(size_t)qB * 2 + dx];
        unsigned xA = *(const unsigned*)(xin + (size_t)(mA & 0xFFFF) * 32 + fp * 2);
        while (q < r1) {
            unsigned xB = *(const unsigned*)(xin + (size_t)(mB & 0xFFFF) * 32 + fp * 2);
            int qC = min(q + 8, last);
            unsigned mC = ejb[qC];
            unsigned wC = ewu[(size_t)qC * 2 + dx];
            float w = h2f((unsigned short)(dy ? (wA >> 16) : (wA & 0xFFFF)));
            int slot = (int)(mA >> 16) + soff;
            int addr = slot * 33 + fp * 2;
            srow[addr]     += w * bf2f((unsigned short)(xA & 0xFFFF));
            srow[addr + 1] += w * bf2f((unsigned short)(xA >> 16));
            mA = mB; wA = wB; xA = xB;
            mB = mC; wB = wC;
            q += 4;
        }
    }
    if (h == 0 && g == 0) {   // fc slot: own features (once per node, partial row 4*nodeb)
        unsigned xv = *(const unsigned*)(xin + (size_t)node * 32 + fp * 2);
        srow[FCOFF + fp * 2]     = bf2f((unsigned short)(xv & 0xFFFF));
        srow[FCOFF + fp * 2 + 1] = bf2f((unsigned short)(xv >> 16));
    }
    __syncthreads();

    if (wv < 2) {
        int row = lane & 15;            // A-row = partial row
        int kb = (lane >> 4) * 8;
        const unsigned short* bp = w2frag + (size_t)wv * NCH * 512 + lane * 8;
        f32x4 acc = {0.f, 0.f, 0.f, 0.f};
#pragma unroll
        for (int c = 0; c < NCH; c++) {
            const float* ap = &s[row][c * 33 + kb];
            short8 av, bv;
#pragma unroll
            for (int i = 0; i < 8; i++) av[i] = (short)f2bf(ap[i]);
            bv = *(const short8*)(bp + (size_t)c * 512);
            acc = __builtin_amdgcn_mfma_f32_16x16x32_bf16(av, bv, acc, 0, 0, 0);
        }
        // D: col=lane&15, row=(lane>>4)*4+r ; rows 4lg..4lg+3 = node lg's partials
        int fo = wv * 16 + (lane & 15);
        int lg = lane >> 4;
        int nd = blockIdx.x * 4 + lg;
        float val = acc[0] + acc[1] + acc[2] + acc[3] + bias[fo];
        if (mode) val += ansbuf[(size_t)nd * 32 + fo];
        if (mode == 2) {
            outf[(size_t)nd * 32 + fo] = val * (1.f / 128.f);
        } else {
            ansbuf[(size_t)nd * 32 + fo] = val;
            xout[(size_t)nd * 32 + fo] = f2bf(fmaxf(val, 0.f));
        }
    }
}

extern "C" void kernel_launch(void* const* d_in, const int* in_sizes, int n_in,
                              void* d_out, int out_size, void* d_ws, size_t ws_size,
                              hipStream_t stream) {
    const float* feat = (const float*)d_in[0];
    const int* ei = (const int*)d_in[1];
    const int* ej = (const int*)d_in[2];
    const float* attr = (const float*)d_in[3];
    WPtrs wp;
    const float* fcB[4];
    if (n_in >= 16) {
        for (int l = 0; l < 4; l++) {
            wp.cw[l] = (const float*)d_in[4 + l];
            wp.fw[l] = (const float*)d_in[8 + l];
            fcB[l]   = (const float*)d_in[12 + l];
        }
    } else {
        const float* cb = (const float*)d_in[4];
        const float* fb = (const float*)d_in[5];
        const float* bb = (const float*)d_in[6];
        for (int l = 0; l < 4; l++) {
            wp.cw[l] = cb + (size_t)l * 16 * 32 * 32;
            wp.fw[l] = fb + (size_t)l * 32 * 32;
            fcB[l]   = bb + (size_t)l * 32;
        }
    }

    char* p = (char*)d_ws;
    auto alloc = [&](size_t bytes) -> void* {
        void* r = (void*)p;
        p += (bytes + 255) & ~(size_t)255;
        return r;
    };
    unsigned short* w2frag = (unsigned short*)alloc((size_t)4 * 2 * NCH * 512 * sizeof(unsigned short));
    unsigned* ejb = (unsigned*)alloc((size_t)NE * sizeof(unsigned));
    uint2* ew     = (uint2*)alloc((size_t)NE * sizeof(uint2));
    int* counts   = (int*)alloc((size_t)NN * sizeof(int));
    int* cursor   = (int*)alloc((size_t)NN * sizeof(int));
    int* rowst    = (int*)alloc((size_t)(NN + 1) * sizeof(int));
    unsigned short* xA = (unsigned short*)alloc((size_t)NN * 32 * sizeof(unsigned short));
    unsigned short* xB = (unsigned short*)alloc((size_t)NN * 32 * sizeof(unsigned short));
    float* ans    = (float*)alloc((size_t)NN * 32 * sizeof(float));
    float* outf   = (float*)d_out;

    hipMemsetAsync(counts, 0, (size_t)NN * sizeof(int), stream);

    histprep_kernel<<<1597, 256, 0, stream>>>(ei, counts, wp, feat, xA, w2frag);
    scan_kernel<<<1, 1024, 0, stream>>>(counts, rowst, cursor);
    fill_kernel<<<(NE + 255) / 256, 256, 0, stream>>>(ei, ej, attr, cursor, ejb, ew);

    size_t wl = (size_t)2 * NCH * 512;
    fused_kernel<<<NN / 4, 1024, 0, stream>>>(xA, xB, ejb, ew, rowst, w2frag + 0 * wl,
                                              fcB[0], ans, outf, 0);
    fused_kernel<<<NN / 4, 1024, 0, stream>>>(xB, xA, ejb, ew, rowst, w2frag + 1 * wl,
                                              fcB[1], ans, outf, 1);
    fused_kernel<<<NN / 4, 1024, 0, stream>>>(xA, xB, ejb, ew, rowst, w2frag + 2 * wl,
                                              fcB[2], ans, outf, 1);
    fused_kernel<<<NN / 4, 1024, 0, stream>>>(xB, xA, ejb, ew, rowst, w2frag + 3 * wl,
                                              fcB[3], ans, outf, 2);
}

// Round 9
// 160.861 us; speedup vs baseline: 1.6993x; 1.6993x over previous
//
#include <hip/hip_runtime.h>
#include <hip/hip_bf16.h>

#define NN 20000
#define NE 320000
#define NCH 17        // 16 conv slots + 1 fc slot, K chunks of 32
#define SROW 561      // per-node LDS row stride (floats): 17*33
#define FCOFF 528     // 16*33: fc slot base within row

typedef __attribute__((ext_vector_type(8))) short short8;
typedef __attribute__((ext_vector_type(4))) float f32x4;

__device__ __forceinline__ unsigned short f2bf(float v) {
    unsigned u = __float_as_uint(v);
    unsigned r = (u + 0x7fffu + ((u >> 16) & 1u)) >> 16;
    return (unsigned short)r;
}
__device__ __forceinline__ float bf2f(unsigned short s) {
    return __uint_as_float(((unsigned)s) << 16);
}
__device__ __forceinline__ unsigned short f2h(float v) {
    union { _Float16 h; unsigned short u; } cv;
    cv.h = (_Float16)v;
    return cv.u;
}
__device__ __forceinline__ float h2f(unsigned short u) {
    union { unsigned short u; _Float16 h; } cv;
    cv.u = u;
    return (float)cv.h;
}

struct WPtrs { const float* cw[4]; const float* fw[4]; };

// ---- fused build: [0,1250) edge histogram; [1250,1563) cast feat->bf16 x0;
//      [1563,1597) build W2frag (pre-swizzled MFMA B-fragments, all 4 layers)
__global__ __launch_bounds__(256) void histprep_kernel(const int* __restrict__ ei,
                                                       int* __restrict__ counts,
                                                       WPtrs wp,
                                                       const float* __restrict__ feat,
                                                       unsigned short* __restrict__ x0,
                                                       unsigned short* __restrict__ w2frag) {
    int b = blockIdx.x, t = threadIdx.x;
    if (b < 1250) {
        int e = b * 256 + t;                     // 1250*256 == NE exactly
        atomicAdd(&counts[ei[e]], 1);
    } else if (b < 1563) {
        int idx = (b - 1250) * 256 + t;          // 80000 groups of 8 elems
        if (idx < 80000) {
            const float4* fsrc = (const float4*)(feat + (size_t)idx * 8);
            float4 a = fsrc[0], c = fsrc[1];
            short8 o;
            o[0] = (short)f2bf(a.x); o[1] = (short)f2bf(a.y);
            o[2] = (short)f2bf(a.z); o[3] = (short)f2bf(a.w);
            o[4] = (short)f2bf(c.x); o[5] = (short)f2bf(c.y);
            o[6] = (short)f2bf(c.z); o[7] = (short)f2bf(c.w);
            *(short8*)(x0 + (size_t)idx * 8) = o;
        }
    } else {
        int id2 = (b - 1563) * 256 + t;          // 4l * 2tile * 17c * 64lane = 8704
        if (id2 < 8704) {
            int lane = id2 & 63;
            int c = (id2 >> 6) % NCH;
            int lt = id2 / (NCH * 64);
            int l = lt >> 1, tt = lt & 1;
            int kb = (lane >> 4) * 8;
            int col = tt * 16 + (lane & 15);
            short8 o;
#pragma unroll
            for (int i = 0; i < 8; i++) {
                int k = c * 32 + kb + i;
                float v = (k < 512) ? wp.cw[l][(size_t)k * 32 + col]
                                    : wp.fw[l][(size_t)(k - 512) * 32 + col];
                o[i] = (short)f2bf(v);
            }
            *(short8*)(w2frag + (size_t)id2 * 8) = o;
        }
    }
}

// ---- CSR build: single-block scan, 20 elements/thread, fully unrolled
__global__ __launch_bounds__(1024) void scan_kernel(const int* __restrict__ counts,
                                                    int* __restrict__ rowst,
                                                    int* __restrict__ cursor) {
    __shared__ int s[1024];
    int t = threadIdx.x;
    int base = t * 20;
    int v[20];
    int sum = 0;
#pragma unroll
    for (int i = 0; i < 20; i++) {
        int idx = base + i;
        v[i] = (idx < NN) ? counts[idx] : 0;
        sum += v[i];
    }
    s[t] = sum;
    __syncthreads();
#pragma unroll
    for (int off = 1; off < 1024; off <<= 1) {
        int add = (t >= off) ? s[t - off] : 0;
        __syncthreads();
        s[t] += add;
        __syncthreads();
    }
    int run = s[t] - sum;
    if (t == 0) rowst[0] = 0;
#pragma unroll
    for (int i = 0; i < 20; i++) {
        int idx = base + i;
        if (idx < NN) {
            cursor[idx] = run;
            rowst[idx + 1] = run + v[i];
        }
        run += v[i];
    }
}

// ---- CSR fill + edge basis precompute (layer-invariant)
// ejb[p] = j | bb<<16 ; ew[p] = { f16x2 w(d=0: lo, d=1: hi), f16x2 w(d=4: lo, d=5: hi) }
__global__ __launch_bounds__(256) void fill_kernel(const int* __restrict__ ei,
                                                   const int* __restrict__ ej,
                                                   const float* __restrict__ attr,
                                                   int* __restrict__ cursor,
                                                   unsigned* __restrict__ ejb,
                                                   uint2* __restrict__ ew) {
    int e = blockIdx.x * 256 + threadIdx.x;
    if (e >= NE) return;
    int i = ei[e], j = ej[e];
    int p = atomicAdd(&cursor[i], 1);
    float2 a = ((const float2*)attr)[e];
    float d0 = fminf(fmaxf(a.x, -1.f), 1.f);
    float d1 = fminf(fmaxf(a.y, -1.f), 1.f);
    float tx = (d0 + 1.f) * 1.5f;
    float ty = (d1 + 1.f) * 1.5f;
    int ix = min(2, max(0, (int)floorf(tx)));
    int iy = min(2, max(0, (int)floorf(ty)));
    float ux = tx - (float)ix;
    float uy = ty - (float)iy;
    float m = (i != j) ? 1.f : 0.f;   // centerIgnore
    uint2 w;
    w.x = (unsigned)f2h((1.f - ux) * (1.f - uy) * m)
        | ((unsigned)f2h((1.f - ux) * uy * m) << 16);
    w.y = (unsigned)f2h(ux * (1.f - uy) * m)
        | ((unsigned)f2h(ux * uy * m) << 16);
    ejb[p] = (unsigned)j | ((unsigned)(ix * 4 + iy) << 16);
    ew[p] = w;
}

// ---- fused layer: 16 nodes/block, 1 wave/node.
// Phase A (scatter-by-MFMA): S_i = Phi_i^T . X_i with K=edges, done as
// mfma_16x16x32 over 32-edge chunks. A[slot][e]=w_e[slot] built in regs
// (bf16 hi+lo pair = exact f16 weights), B[e][f]=x_j[f] gathered 2B/lane.
// D (16 slots x 32 feats, f32) written once to LDS -- no RMW, no zero-init.
// Phase B: waves 0,1 compute ans = S . W2 (17 MFMA) +bias/residual/relu.
__global__ __launch_bounds__(1024, 8) void fused_kernel(const unsigned short* __restrict__ xin,
                                                        unsigned short* __restrict__ xout,
                                                        const unsigned* __restrict__ ejb,
                                                        const uint2* __restrict__ ew,
                                                        const int* __restrict__ rowst,
                                                        const unsigned short* __restrict__ w2frag,
                                                        const float* __restrict__ bias,
                                                        float* __restrict__ ansbuf,
                                                        float* __restrict__ outf,
                                                        int mode) {
    __shared__ float s[16][SROW];
    int tid = threadIdx.x;
    int wv = tid >> 6, lane = tid & 63;
    int fcol = lane & 15;              // A-row (slot) / B-col (feature) role
    int kg = lane >> 4;                // edge octet within chunk
    int node = blockIdx.x * 16 + wv;
    int r0 = rowst[node], r1 = rowst[node + 1];

    f32x4 acc0 = {0.f, 0.f, 0.f, 0.f};
    f32x4 acc1 = {0.f, 0.f, 0.f, 0.f};

    for (int qb = r0; qb < r1; qb += 32) {
        int last = r1 - 1;
        int qa = qb + kg * 8;
        unsigned mm[8];
#pragma unroll
        for (int i = 0; i < 8; i++) mm[i] = ejb[min(qa + i, last)];
        short8 avhi, avlo, bv0, bv1;
#pragma unroll
        for (int i = 0; i < 8; i++) {
            int qc = min(qa + i, last);
            uint2 wpair = ew[qc];
            int j = (int)(mm[i] & 0xFFFF);
            bv0[i] = (short)xin[(size_t)j * 32 + fcol];
            bv1[i] = (short)xin[(size_t)j * 32 + 16 + fcol];
            int d = fcol - (int)(mm[i] >> 16);
            unsigned bits = (d == 0) ? (wpair.x & 0xFFFFu)
                          : (d == 1) ? (wpair.x >> 16)
                          : (d == 4) ? (wpair.y & 0xFFFFu)
                          : (d == 5) ? (wpair.y >> 16) : 0u;
            if (qa + i >= r1) bits = 0u;
            float wf = h2f((unsigned short)bits);
            unsigned short whi = f2bf(wf);
            float wlo = wf - bf2f(whi);
            avhi[i] = (short)whi;
            avlo[i] = (short)f2bf(wlo);
        }
        acc0 = __builtin_amdgcn_mfma_f32_16x16x32_bf16(avhi, bv0, acc0, 0, 0, 0);
        acc0 = __builtin_amdgcn_mfma_f32_16x16x32_bf16(avlo, bv0, acc0, 0, 0, 0);
        acc1 = __builtin_amdgcn_mfma_f32_16x16x32_bf16(avhi, bv1, acc1, 0, 0, 0);
        acc1 = __builtin_amdgcn_mfma_f32_16x16x32_bf16(avlo, bv1, acc1, 0, 0, 0);
    }
    // D -> LDS: lane holds D[slotrow = kg*4+r][feat = fcol] (+16 for frag1)
#pragma unroll
    for (int r = 0; r < 4; r++) {
        int sr = kg * 4 + r;
        s[wv][sr * 33 + fcol]      = acc0[r];
        s[wv][sr * 33 + 16 + fcol] = acc1[r];
    }
    if (lane < 32) {   // fc slot: own features
        s[wv][FCOFF + lane] = bf2f(xin[(size_t)node * 32 + lane]);
    }
    __syncthreads();

    if (wv < 2) {
        int row = lane & 15;            // A-row = node within block
        int kb = (lane >> 4) * 8;
        const unsigned short* bp = w2frag + (size_t)wv * NCH * 512 + lane * 8;
        f32x4 acc = {0.f, 0.f, 0.f, 0.f};
#pragma unroll
        for (int c = 0; c < NCH; c++) {
            const float* ap = &s[row][c * 33 + kb];
            short8 av, bv;
#pragma unroll
            for (int i = 0; i < 8; i++) av[i] = (short)f2bf(ap[i]);
            bv = *(const short8*)(bp + (size_t)c * 512);
            acc = __builtin_amdgcn_mfma_f32_16x16x32_bf16(av, bv, acc, 0, 0, 0);
        }
        // D: col=lane&15 (feature), row=(lane>>4)*4+r (node within block)
        int fo = wv * 16 + (lane & 15);
        float bs = bias[fo];
#pragma unroll
        for (int r = 0; r < 4; r++) {
            int nd = blockIdx.x * 16 + (lane >> 4) * 4 + r;
            float val = acc[r] + bs;
            if (mode) val += ansbuf[(size_t)nd * 32 + fo];
            if (mode == 2) {
                outf[(size_t)nd * 32 + fo] = val * (1.f / 128.f);
            } else {
                ansbuf[(size_t)nd * 32 + fo] = val;
                xout[(size_t)nd * 32 + fo] = f2bf(fmaxf(val, 0.f));
            }
        }
    }
}

extern "C" void kernel_launch(void* const* d_in, const int* in_sizes, int n_in,
                              void* d_out, int out_size, void* d_ws, size_t ws_size,
                              hipStream_t stream) {
    const float* feat = (const float*)d_in[0];
    const int* ei = (const int*)d_in[1];
    const int* ej = (const int*)d_in[2];
    const float* attr = (const float*)d_in[3];
    WPtrs wp;
    const float* fcB[4];
    if (n_in >= 16) {
        for (int l = 0; l < 4; l++) {
            wp.cw[l] = (const float*)d_in[4 + l];
            wp.fw[l] = (const float*)d_in[8 + l];
            fcB[l]   = (const float*)d_in[12 + l];
        }
    } else {
        const float* cb = (const float*)d_in[4];
        const float* fb = (const float*)d_in[5];
        const float* bb = (const float*)d_in[6];
        for (int l = 0; l < 4; l++) {
            wp.cw[l] = cb + (size_t)l * 16 * 32 * 32;
            wp.fw[l] = fb + (size_t)l * 32 * 32;
            fcB[l]   = bb + (size_t)l * 32;
        }
    }

    char* p = (char*)d_ws;
    auto alloc = [&](size_t bytes) -> void* {
        void* r = (void*)p;
        p += (bytes + 255) & ~(size_t)255;
        return r;
    };
    unsigned short* w2frag = (unsigned short*)alloc((size_t)4 * 2 * NCH * 512 * sizeof(unsigned short));
    unsigned* ejb = (unsigned*)alloc((size_t)NE * sizeof(unsigned));
    uint2* ew     = (uint2*)alloc((size_t)NE * sizeof(uint2));
    int* counts   = (int*)alloc((size_t)NN * sizeof(int));
    int* cursor   = (int*)alloc((size_t)NN * sizeof(int));
    int* rowst    = (int*)alloc((size_t)(NN + 1) * sizeof(int));
    unsigned short* xA = (unsigned short*)alloc((size_t)NN * 32 * sizeof(unsigned short));
    unsigned short* xB = (unsigned short*)alloc((size_t)NN * 32 * sizeof(unsigned short));
    float* ans    = (float*)alloc((size_t)NN * 32 * sizeof(float));
    float* outf   = (float*)d_out;

    hipMemsetAsync(counts, 0, (size_t)NN * sizeof(int), stream);

    histprep_kernel<<<1597, 256, 0, stream>>>(ei, counts, wp, feat, xA, w2frag);
    scan_kernel<<<1, 1024, 0, stream>>>(counts, rowst, cursor);
    fill_kernel<<<(NE + 255) / 256, 256, 0, stream>>>(ei, ej, attr, cursor, ejb, ew);

    size_t wl = (size_t)2 * NCH * 512;
    fused_kernel<<<NN / 16, 1024, 0, stream>>>(xA, xB, ejb, ew, rowst, w2frag + 0 * wl,
                                               fcB[0], ans, outf, 0);
    fused_kernel<<<NN / 16, 1024, 0, stream>>>(xB, xA, ejb, ew, rowst, w2frag + 1 * wl,
                                               fcB[1], ans, outf, 1);
    fused_kernel<<<NN / 16, 1024, 0, stream>>>(xA, xB, ejb, ew, rowst, w2frag + 2 * wl,
                                               fcB[2], ans, outf, 1);
    fused_kernel<<<NN / 16, 1024, 0, stream>>>(xB, xA, ejb, ew, rowst, w2frag + 3 * wl,
                                               fcB[3], ans, outf, 2);
}

// Round 10
// 153.055 us; speedup vs baseline: 1.7860x; 1.0510x over previous
//
#include <hip/hip_runtime.h>
#include <hip/hip_bf16.h>

#define NN 20000
#define NE 320000
#define NCH 17        // 16 conv slots + 1 fc slot, K chunks of 32
#define SROW 561      // per-node LDS row stride (floats): 17*33
#define FCOFF 528     // 16*33: fc slot base within row

typedef __attribute__((ext_vector_type(8))) short short8;
typedef __attribute__((ext_vector_type(4))) float f32x4;

__device__ __forceinline__ unsigned short f2bf(float v) {
    unsigned u = __float_as_uint(v);
    unsigned r = (u + 0x7fffu + ((u >> 16) & 1u)) >> 16;
    return (unsigned short)r;
}
__device__ __forceinline__ float bf2f(unsigned short s) {
    return __uint_as_float(((unsigned)s) << 16);
}
__device__ __forceinline__ unsigned short f2h(float v) {
    union { _Float16 h; unsigned short u; } cv;
    cv.h = (_Float16)v;
    return cv.u;
}
__device__ __forceinline__ float h2f(unsigned short u) {
    union { unsigned short u; _Float16 h; } cv;
    cv.u = u;
    return (float)cv.h;
}

struct WPtrs { const float* cw[4]; const float* fw[4]; };

// x layout: per node 16 dwords; dword f = bf16(x[f]) | bf16(x[f+16])<<16

// ---- fused build: [0,1250) edge histogram; [1250,1329) cast feat->interleaved bf16;
//      [1329,1363) build W2frag (pre-swizzled MFMA B-fragments, all 4 layers)
__global__ __launch_bounds__(256) void histprep_kernel(const int* __restrict__ ei,
                                                       int* __restrict__ counts,
                                                       WPtrs wp,
                                                       const float* __restrict__ feat,
                                                       unsigned* __restrict__ x0,
                                                       unsigned short* __restrict__ w2frag) {
    int b = blockIdx.x, t = threadIdx.x;
    if (b < 1250) {
        int e = b * 256 + t;                     // 1250*256 == NE exactly
        atomicAdd(&counts[ei[e]], 1);
    } else if (b < 1329) {
        int n = (b - 1250) * 256 + t;
        if (n < NN) {
            const float4* fr = (const float4*)(feat + (size_t)n * 32);
            float4 v0 = fr[0], v1 = fr[1], v2 = fr[2], v3 = fr[3];
            float4 v4 = fr[4], v5 = fr[5], v6 = fr[6], v7 = fr[7];
            float lo[16] = {v0.x, v0.y, v0.z, v0.w, v1.x, v1.y, v1.z, v1.w,
                            v2.x, v2.y, v2.z, v2.w, v3.x, v3.y, v3.z, v3.w};
            float hi[16] = {v4.x, v4.y, v4.z, v4.w, v5.x, v5.y, v5.z, v5.w,
                            v6.x, v6.y, v6.z, v6.w, v7.x, v7.y, v7.z, v7.w};
            unsigned o[16];
#pragma unroll
            for (int f = 0; f < 16; f++)
                o[f] = (unsigned)f2bf(lo[f]) | ((unsigned)f2bf(hi[f]) << 16);
            uint4* dst = (uint4*)(x0 + (size_t)n * 16);
#pragma unroll
            for (int q = 0; q < 4; q++) {
                uint4 w; w.x = o[q*4]; w.y = o[q*4+1]; w.z = o[q*4+2]; w.w = o[q*4+3];
                dst[q] = w;
            }
        }
    } else {
        int id2 = (b - 1329) * 256 + t;          // 4l * 2tile * 17c * 64lane = 8704
        if (id2 < 8704) {
            int lane = id2 & 63;
            int c = (id2 >> 6) % NCH;
            int lt = id2 / (NCH * 64);
            int l = lt >> 1, tt = lt & 1;
            int kb = (lane >> 4) * 8;
            int col = tt * 16 + (lane & 15);
            short8 o;
#pragma unroll
            for (int i = 0; i < 8; i++) {
                int k = c * 32 + kb + i;
                float v = (k < 512) ? wp.cw[l][(size_t)k * 32 + col]
                                    : wp.fw[l][(size_t)(k - 512) * 32 + col];
                o[i] = (short)f2bf(v);
            }
            *(short8*)(w2frag + (size_t)id2 * 8) = o;
        }
    }
}

// ---- CSR build: single-block scan, 20 elements/thread, fully unrolled
__global__ __launch_bounds__(1024) void scan_kernel(const int* __restrict__ counts,
                                                    int* __restrict__ rowst,
                                                    int* __restrict__ cursor) {
    __shared__ int s[1024];
    int t = threadIdx.x;
    int base = t * 20;
    int v[20];
    int sum = 0;
#pragma unroll
    for (int i = 0; i < 20; i++) {
        int idx = base + i;
        v[i] = (idx < NN) ? counts[idx] : 0;
        sum += v[i];
    }
    s[t] = sum;
    __syncthreads();
#pragma unroll
    for (int off = 1; off < 1024; off <<= 1) {
        int add = (t >= off) ? s[t - off] : 0;
        __syncthreads();
        s[t] += add;
        __syncthreads();
    }
    int run = s[t] - sum;
    if (t == 0) rowst[0] = 0;
#pragma unroll
    for (int i = 0; i < 20; i++) {
        int idx = base + i;
        if (idx < NN) {
            cursor[idx] = run;
            rowst[idx + 1] = run + v[i];
        }
        run += v[i];
    }
}

// ---- CSR fill + edge basis precompute (layer-invariant)
// emeta[p] = { j | bb<<16, f16x2 w(d0 lo, d1 hi), f16x2 w(d4 lo, d5 hi), 0 }
__global__ __launch_bounds__(256) void fill_kernel(const int* __restrict__ ei,
                                                   const int* __restrict__ ej,
                                                   const float* __restrict__ attr,
                                                   int* __restrict__ cursor,
                                                   uint4* __restrict__ emeta) {
    int e = blockIdx.x * 256 + threadIdx.x;
    if (e >= NE) return;
    int i = ei[e], j = ej[e];
    int p = atomicAdd(&cursor[i], 1);
    float2 a = ((const float2*)attr)[e];
    float d0 = fminf(fmaxf(a.x, -1.f), 1.f);
    float d1 = fminf(fmaxf(a.y, -1.f), 1.f);
    float tx = (d0 + 1.f) * 1.5f;
    float ty = (d1 + 1.f) * 1.5f;
    int ix = min(2, max(0, (int)floorf(tx)));
    int iy = min(2, max(0, (int)floorf(ty)));
    float ux = tx - (float)ix;
    float uy = ty - (float)iy;
    float m = (i != j) ? 1.f : 0.f;   // centerIgnore
    uint4 mm;
    mm.x = (unsigned)j | ((unsigned)(ix * 4 + iy) << 16);
    mm.y = (unsigned)f2h((1.f - ux) * (1.f - uy) * m)
         | ((unsigned)f2h((1.f - ux) * uy * m) << 16);
    mm.z = (unsigned)f2h(ux * (1.f - uy) * m)
         | ((unsigned)f2h(ux * uy * m) << 16);
    mm.w = 0;
    emeta[p] = mm;
}

// ---- fused layer: 16 nodes/block, 1 wave/node.
// Phase A (scatter-by-MFMA): S_i = Phi_i^T . X_i with K=edges, one
// mfma_16x16x32 pair (bf16 hi+lo = exact f16 weights) per 32-edge chunk.
// A[slot][e] built in regs; B[e][f] = ONE dword gather (features f and f+16).
// D written once to LDS -- no RMW, no zero-init.
// Phase B: waves 0,1 compute ans = S . W2 (17 MFMA) +bias/residual/relu.
__global__ __launch_bounds__(1024, 8) void fused_kernel(const unsigned* __restrict__ xin,
                                                        unsigned short* __restrict__ xout,
                                                        const uint4* __restrict__ emeta,
                                                        const int* __restrict__ rowst,
                                                        const unsigned short* __restrict__ w2frag,
                                                        const float* __restrict__ bias,
                                                        float* __restrict__ ansbuf,
                                                        float* __restrict__ outf,
                                                        int mode) {
    __shared__ float s[16][SROW];
    int tid = threadIdx.x;
    int wv = tid >> 6, lane = tid & 63;
    int fcol = lane & 15;              // A-row (slot) / B-col (feature) role
    int kg = lane >> 4;                // edge octet within chunk
    int node = blockIdx.x * 16 + wv;
    int r0 = rowst[node], r1 = rowst[node + 1];

    f32x4 acc0 = {0.f, 0.f, 0.f, 0.f};
    f32x4 acc1 = {0.f, 0.f, 0.f, 0.f};

    for (int qb = r0; qb < r1; qb += 32) {
        int last = r1 - 1;
        int qa = qb + kg * 8;
        uint4 mm[8];
#pragma unroll
        for (int i = 0; i < 8; i++) mm[i] = emeta[min(qa + i, last)];
        unsigned xv[8];
#pragma unroll
        for (int i = 0; i < 8; i++)
            xv[i] = xin[(size_t)(mm[i].x & 0xFFFF) * 16 + fcol];
        short8 avhi, avlo, bv0, bv1;
#pragma unroll
        for (int i = 0; i < 8; i++) {
            bv0[i] = (short)(unsigned short)(xv[i] & 0xFFFF);
            bv1[i] = (short)(unsigned short)(xv[i] >> 16);
            int d = fcol - (int)(mm[i].x >> 16);
            unsigned bits = (d == 0) ? (mm[i].y & 0xFFFFu)
                          : (d == 1) ? (mm[i].y >> 16)
                          : (d == 4) ? (mm[i].z & 0xFFFFu)
                          : (d == 5) ? (mm[i].z >> 16) : 0u;
            if (qa + i >= r1) bits = 0u;
            float wf = h2f((unsigned short)bits);
            unsigned short whi = f2bf(wf);
            float wlo = wf - bf2f(whi);
            avhi[i] = (short)whi;
            avlo[i] = (short)f2bf(wlo);
        }
        acc0 = __builtin_amdgcn_mfma_f32_16x16x32_bf16(avhi, bv0, acc0, 0, 0, 0);
        acc0 = __builtin_amdgcn_mfma_f32_16x16x32_bf16(avlo, bv0, acc0, 0, 0, 0);
        acc1 = __builtin_amdgcn_mfma_f32_16x16x32_bf16(avhi, bv1, acc1, 0, 0, 0);
        acc1 = __builtin_amdgcn_mfma_f32_16x16x32_bf16(avlo, bv1, acc1, 0, 0, 0);
    }
    // D -> LDS: lane holds D[slotrow = kg*4+r][feat = fcol] (+16 for frag1)
#pragma unroll
    for (int r = 0; r < 4; r++) {
        int sr = kg * 4 + r;
        s[wv][sr * 33 + fcol]      = acc0[r];
        s[wv][sr * 33 + 16 + fcol] = acc1[r];
    }
    if (lane < 32) {   // fc slot: own features (de-interleave)
        unsigned xv = xin[(size_t)node * 16 + (lane & 15)];
        s[wv][FCOFF + lane] = bf2f((unsigned short)((lane < 16) ? (xv & 0xFFFF) : (xv >> 16)));
    }
    __syncthreads();

    if (wv < 2) {
        int row = lane & 15;            // A-row = node within block
        int kb = (lane >> 4) * 8;
        const unsigned short* bp = w2frag + (size_t)wv * NCH * 512 + lane * 8;
        f32x4 acc = {0.f, 0.f, 0.f, 0.f};
#pragma unroll
        for (int c = 0; c < NCH; c++) {
            const float* ap = &s[row][c * 33 + kb];
            short8 av, bv;
#pragma unroll
            for (int i = 0; i < 8; i++) av[i] = (short)f2bf(ap[i]);
            bv = *(const short8*)(bp + (size_t)c * 512);
            acc = __builtin_amdgcn_mfma_f32_16x16x32_bf16(av, bv, acc, 0, 0, 0);
        }
        // D: col=lane&15 (feature), row=(lane>>4)*4+r (node within block)
        int fo = wv * 16 + (lane & 15);
        float bs = bias[fo];
        // interleaved xout position (ushort index within node): (fo&15)*2 + (fo>>4)
        int xpos = (fo & 15) * 2 + (fo >> 4);
#pragma unroll
        for (int r = 0; r < 4; r++) {
            int nd = blockIdx.x * 16 + (lane >> 4) * 4 + r;
            float val = acc[r] + bs;
            if (mode) val += ansbuf[(size_t)nd * 32 + fo];
            if (mode == 2) {
                outf[(size_t)nd * 32 + fo] = val * (1.f / 128.f);
            } else {
                ansbuf[(size_t)nd * 32 + fo] = val;
                xout[(size_t)nd * 32 + xpos] = f2bf(fmaxf(val, 0.f));
            }
        }
    }
}

extern "C" void kernel_launch(void* const* d_in, const int* in_sizes, int n_in,
                              void* d_out, int out_size, void* d_ws, size_t ws_size,
                              hipStream_t stream) {
    const float* feat = (const float*)d_in[0];
    const int* ei = (const int*)d_in[1];
    const int* ej = (const int*)d_in[2];
    const float* attr = (const float*)d_in[3];
    WPtrs wp;
    const float* fcB[4];
    if (n_in >= 16) {
        for (int l = 0; l < 4; l++) {
            wp.cw[l] = (const float*)d_in[4 + l];
            wp.fw[l] = (const float*)d_in[8 + l];
            fcB[l]   = (const float*)d_in[12 + l];
        }
    } else {
        const float* cb = (const float*)d_in[4];
        const float* fb = (const float*)d_in[5];
        const float* bb = (const float*)d_in[6];
        for (int l = 0; l < 4; l++) {
            wp.cw[l] = cb + (size_t)l * 16 * 32 * 32;
            wp.fw[l] = fb + (size_t)l * 32 * 32;
            fcB[l]   = bb + (size_t)l * 32;
        }
    }

    char* p = (char*)d_ws;
    auto alloc = [&](size_t bytes) -> void* {
        void* r = (void*)p;
        p += (bytes + 255) & ~(size_t)255;
        return r;
    };
    unsigned short* w2frag = (unsigned short*)alloc((size_t)4 * 2 * NCH * 512 * sizeof(unsigned short));
    uint4* emeta  = (uint4*)alloc((size_t)NE * sizeof(uint4));
    int* counts   = (int*)alloc((size_t)NN * sizeof(int));
    int* cursor   = (int*)alloc((size_t)NN * sizeof(int));
    int* rowst    = (int*)alloc((size_t)(NN + 1) * sizeof(int));
    unsigned* xA  = (unsigned*)alloc((size_t)NN * 16 * sizeof(unsigned));
    unsigned* xB  = (unsigned*)alloc((size_t)NN * 16 * sizeof(unsigned));
    float* ans    = (float*)alloc((size_t)NN * 32 * sizeof(float));
    float* outf   = (float*)d_out;

    hipMemsetAsync(counts, 0, (size_t)NN * sizeof(int), stream);

    histprep_kernel<<<1363, 256, 0, stream>>>(ei, counts, wp, feat, xA, w2frag);
    scan_kernel<<<1, 1024, 0, stream>>>(counts, rowst, cursor);
    fill_kernel<<<(NE + 255) / 256, 256, 0, stream>>>(ei, ej, attr, cursor, emeta);

    size_t wl = (size_t)2 * NCH * 512;
    fused_kernel<<<NN / 16, 1024, 0, stream>>>(xA, (unsigned short*)xB, emeta, rowst,
                                               w2frag + 0 * wl, fcB[0], ans, outf, 0);
    fused_kernel<<<NN / 16, 1024, 0, stream>>>(xB, (unsigned short*)xA, emeta, rowst,
                                               w2frag + 1 * wl, fcB[1], ans, outf, 1);
    fused_kernel<<<NN / 16, 1024, 0, stream>>>(xA, (unsigned short*)xB, emeta, rowst,
                                               w2frag + 2 * wl, fcB[2], ans, outf, 1);
    fused_kernel<<<NN / 16, 1024, 0, stream>>>(xB, (unsigned short*)xA, emeta, rowst,
                                               w2frag + 3 * wl, fcB[3], ans, outf, 2);
}

// Round 11
// 147.957 us; speedup vs baseline: 1.8475x; 1.0345x over previous
//
#include <hip/hip_runtime.h>
#include <hip/hip_bf16.h>

#define NN 20000
#define NE 320000
#define NCH 17        // 16 conv slots + 1 fc slot, K chunks of 32
#define SROW 561      // per-node LDS row stride (floats): 17*33
#define FCOFF 528     // 16*33: fc slot base within row

typedef __attribute__((ext_vector_type(8))) short short8;
typedef __attribute__((ext_vector_type(4))) float f32x4;

__device__ __forceinline__ unsigned short f2bf(float v) {
    unsigned u = __float_as_uint(v);
    unsigned r = (u + 0x7fffu + ((u >> 16) & 1u)) >> 16;
    return (unsigned short)r;
}
__device__ __forceinline__ float bf2f(unsigned short s) {
    return __uint_as_float(((unsigned)s) << 16);
}

struct WPtrs { const float* cw[4]; const float* fw[4]; };

// x layout: per node 16 dwords; dword f = bf16(x[f]) | bf16(x[f+16])<<16

// ---- fused build: [0,1250) edge histogram; [1250,1329) cast feat->interleaved bf16;
//      [1329,1363) build W2frag (pre-swizzled MFMA B-fragments, all 4 layers)
__global__ __launch_bounds__(256) void histprep_kernel(const int* __restrict__ ei,
                                                       int* __restrict__ counts,
                                                       WPtrs wp,
                                                       const float* __restrict__ feat,
                                                       unsigned* __restrict__ x0,
                                                       unsigned short* __restrict__ w2frag) {
    int b = blockIdx.x, t = threadIdx.x;
    if (b < 1250) {
        int e = b * 256 + t;                     // 1250*256 == NE exactly
        atomicAdd(&counts[ei[e]], 1);
    } else if (b < 1329) {
        int n = (b - 1250) * 256 + t;
        if (n < NN) {
            const float4* fr = (const float4*)(feat + (size_t)n * 32);
            float4 v0 = fr[0], v1 = fr[1], v2 = fr[2], v3 = fr[3];
            float4 v4 = fr[4], v5 = fr[5], v6 = fr[6], v7 = fr[7];
            float lo[16] = {v0.x, v0.y, v0.z, v0.w, v1.x, v1.y, v1.z, v1.w,
                            v2.x, v2.y, v2.z, v2.w, v3.x, v3.y, v3.z, v3.w};
            float hi[16] = {v4.x, v4.y, v4.z, v4.w, v5.x, v5.y, v5.z, v5.w,
                            v6.x, v6.y, v6.z, v6.w, v7.x, v7.y, v7.z, v7.w};
            unsigned o[16];
#pragma unroll
            for (int f = 0; f < 16; f++)
                o[f] = (unsigned)f2bf(lo[f]) | ((unsigned)f2bf(hi[f]) << 16);
            uint4* dst = (uint4*)(x0 + (size_t)n * 16);
#pragma unroll
            for (int q = 0; q < 4; q++) {
                uint4 w; w.x = o[q*4]; w.y = o[q*4+1]; w.z = o[q*4+2]; w.w = o[q*4+3];
                dst[q] = w;
            }
        }
    } else {
        int id2 = (b - 1329) * 256 + t;          // 4l * 2tile * 17c * 64lane = 8704
        if (id2 < 8704) {
            int lane = id2 & 63;
            int c = (id2 >> 6) % NCH;
            int lt = id2 / (NCH * 64);
            int l = lt >> 1, tt = lt & 1;
            int kb = (lane >> 4) * 8;
            int col = tt * 16 + (lane & 15);
            short8 o;
#pragma unroll
            for (int i = 0; i < 8; i++) {
                int k = c * 32 + kb + i;
                float v = (k < 512) ? wp.cw[l][(size_t)k * 32 + col]
                                    : wp.fw[l][(size_t)(k - 512) * 32 + col];
                o[i] = (short)f2bf(v);
            }
            *(short8*)(w2frag + (size_t)id2 * 8) = o;
        }
    }
}

// ---- CSR build: single-block scan, 20 elements/thread, fully unrolled
__global__ __launch_bounds__(1024) void scan_kernel(const int* __restrict__ counts,
                                                    int* __restrict__ rowst,
                                                    int* __restrict__ cursor) {
    __shared__ int s[1024];
    int t = threadIdx.x;
    int base = t * 20;
    int v[20];
    int sum = 0;
#pragma unroll
    for (int i = 0; i < 20; i++) {
        int idx = base + i;
        v[i] = (idx < NN) ? counts[idx] : 0;
        sum += v[i];
    }
    s[t] = sum;
    __syncthreads();
#pragma unroll
    for (int off = 1; off < 1024; off <<= 1) {
        int add = (t >= off) ? s[t - off] : 0;
        __syncthreads();
        s[t] += add;
        __syncthreads();
    }
    int run = s[t] - sum;
    if (t == 0) rowst[0] = 0;
#pragma unroll
    for (int i = 0; i < 20; i++) {
        int idx = base + i;
        if (idx < NN) {
            cursor[idx] = run;
            rowst[idx + 1] = run + v[i];
        }
        run += v[i];
    }
}

// ---- CSR fill + edge basis precompute (layer-invariant)
// emeta[p] = { j | bb<<16, bf16x2 w(d0 lo, d1 hi), bf16x2 w(d4 lo, d5 hi), 0 }
__global__ __launch_bounds__(256) void fill_kernel(const int* __restrict__ ei,
                                                   const int* __restrict__ ej,
                                                   const float* __restrict__ attr,
                                                   int* __restrict__ cursor,
                                                   uint4* __restrict__ emeta) {
    int e = blockIdx.x * 256 + threadIdx.x;
    if (e >= NE) return;
    int i = ei[e], j = ej[e];
    int p = atomicAdd(&cursor[i], 1);
    float2 a = ((const float2*)attr)[e];
    float d0 = fminf(fmaxf(a.x, -1.f), 1.f);
    float d1 = fminf(fmaxf(a.y, -1.f), 1.f);
    float tx = (d0 + 1.f) * 1.5f;
    float ty = (d1 + 1.f) * 1.5f;
    int ix = min(2, max(0, (int)floorf(tx)));
    int iy = min(2, max(0, (int)floorf(ty)));
    float ux = tx - (float)ix;
    float uy = ty - (float)iy;
    float m = (i != j) ? 1.f : 0.f;   // centerIgnore
    uint4 mm;
    mm.x = (unsigned)j | ((unsigned)(ix * 4 + iy) << 16);
    mm.y = (unsigned)f2bf((1.f - ux) * (1.f - uy) * m)
         | ((unsigned)f2bf((1.f - ux) * uy * m) << 16);
    mm.z = (unsigned)f2bf(ux * (1.f - uy) * m)
         | ((unsigned)f2bf(ux * uy * m) << 16);
    mm.w = 0;
    emeta[p] = mm;
}

// ---- fused layer: 16 nodes/block, 1 wave/node.
// Phase A (scatter-by-MFMA): S_i = Phi_i^T . X_i with K=edges, one
// mfma_16x16x32 per B-fragment per 32-edge chunk (weights pre-bf16 in emeta).
// A[slot][e] built by select; B[e][f] = ONE dword gather (features f and f+16).
// D written once to LDS -- no RMW, no zero-init.
// Phase B: waves 0,1 compute ans = S . W2 (17 MFMA) +bias/residual/relu.
__global__ __launch_bounds__(1024, 8) void fused_kernel(const unsigned* __restrict__ xin,
                                                        unsigned short* __restrict__ xout,
                                                        const uint4* __restrict__ emeta,
                                                        const int* __restrict__ rowst,
                                                        const unsigned short* __restrict__ w2frag,
                                                        const float* __restrict__ bias,
                                                        float* __restrict__ ansbuf,
                                                        float* __restrict__ outf,
                                                        int mode) {
    __shared__ float s[16][SROW];
    int tid = threadIdx.x;
    int wv = tid >> 6, lane = tid & 63;
    int fcol = lane & 15;              // A-row (slot) / B-col (feature) role
    int kg = lane >> 4;                // edge octet within chunk
    int node = blockIdx.x * 16 + wv;
    int r0 = rowst[node], r1 = rowst[node + 1];

    f32x4 acc0 = {0.f, 0.f, 0.f, 0.f};
    f32x4 acc1 = {0.f, 0.f, 0.f, 0.f};

    for (int qb = r0; qb < r1; qb += 32) {
        int last = r1 - 1;
        int qa = qb + kg * 8;
        uint4 mm[8];
#pragma unroll
        for (int i = 0; i < 8; i++) mm[i] = emeta[min(qa + i, last)];
        unsigned xv[8];
#pragma unroll
        for (int i = 0; i < 8; i++)
            xv[i] = xin[(size_t)(mm[i].x & 0xFFFF) * 16 + fcol];
        short8 av, bv0, bv1;
#pragma unroll
        for (int i = 0; i < 8; i++) {
            bv0[i] = (short)(unsigned short)(xv[i] & 0xFFFF);
            bv1[i] = (short)(unsigned short)(xv[i] >> 16);
            int d = fcol - (int)(mm[i].x >> 16);
            unsigned bits = (d == 0) ? (mm[i].y & 0xFFFFu)
                          : (d == 1) ? (mm[i].y >> 16)
                          : (d == 4) ? (mm[i].z & 0xFFFFu)
                          : (d == 5) ? (mm[i].z >> 16) : 0u;
            if (qa + i >= r1) bits = 0u;
            av[i] = (short)bits;
        }
        acc0 = __builtin_amdgcn_mfma_f32_16x16x32_bf16(av, bv0, acc0, 0, 0, 0);
        acc1 = __builtin_amdgcn_mfma_f32_16x16x32_bf16(av, bv1, acc1, 0, 0, 0);
    }
    // D -> LDS: lane holds D[slotrow = kg*4+r][feat = fcol] (+16 for frag1)
#pragma unroll
    for (int r = 0; r < 4; r++) {
        int sr = kg * 4 + r;
        s[wv][sr * 33 + fcol]      = acc0[r];
        s[wv][sr * 33 + 16 + fcol] = acc1[r];
    }
    if (lane < 32) {   // fc slot: own features (de-interleave)
        unsigned xv = xin[(size_t)node * 16 + (lane & 15)];
        s[wv][FCOFF + lane] = bf2f((unsigned short)((lane < 16) ? (xv & 0xFFFF) : (xv >> 16)));
    }
    __syncthreads();

    if (wv < 2) {
        int row = lane & 15;            // A-row = node within block
        int kb = (lane >> 4) * 8;
        const unsigned short* bp = w2frag + (size_t)wv * NCH * 512 + lane * 8;
        f32x4 acc = {0.f, 0.f, 0.f, 0.f};
#pragma unroll
        for (int c = 0; c < NCH; c++) {
            const float* ap = &s[row][c * 33 + kb];
            short8 av, bv;
#pragma unroll
            for (int i = 0; i < 8; i++) av[i] = (short)f2bf(ap[i]);
            bv = *(const short8*)(bp + (size_t)c * 512);
            acc = __builtin_amdgcn_mfma_f32_16x16x32_bf16(av, bv, acc, 0, 0, 0);
        }
        // D: col=lane&15 (feature), row=(lane>>4)*4+r (node within block)
        int fo = wv * 16 + (lane & 15);
        float bs = bias[fo];
        // interleaved xout position (ushort index within node): (fo&15)*2 + (fo>>4)
        int xpos = (fo & 15) * 2 + (fo >> 4);
#pragma unroll
        for (int r = 0; r < 4; r++) {
            int nd = blockIdx.x * 16 + (lane >> 4) * 4 + r;
            float val = acc[r] + bs;
            if (mode) val += ansbuf[(size_t)nd * 32 + fo];
            if (mode == 2) {
                outf[(size_t)nd * 32 + fo] = val * (1.f / 128.f);
            } else {
                ansbuf[(size_t)nd * 32 + fo] = val;
                xout[(size_t)nd * 32 + xpos] = f2bf(fmaxf(val, 0.f));
            }
        }
    }
}

extern "C" void kernel_launch(void* const* d_in, const int* in_sizes, int n_in,
                              void* d_out, int out_size, void* d_ws, size_t ws_size,
                              hipStream_t stream) {
    const float* feat = (const float*)d_in[0];
    const int* ei = (const int*)d_in[1];
    const int* ej = (const int*)d_in[2];
    const float* attr = (const float*)d_in[3];
    WPtrs wp;
    const float* fcB[4];
    if (n_in >= 16) {
        for (int l = 0; l < 4; l++) {
            wp.cw[l] = (const float*)d_in[4 + l];
            wp.fw[l] = (const float*)d_in[8 + l];
            fcB[l]   = (const float*)d_in[12 + l];
        }
    } else {
        const float* cb = (const float*)d_in[4];
        const float* fb = (const float*)d_in[5];
        const float* bb = (const float*)d_in[6];
        for (int l = 0; l < 4; l++) {
            wp.cw[l] = cb + (size_t)l * 16 * 32 * 32;
            wp.fw[l] = fb + (size_t)l * 32 * 32;
            fcB[l]   = bb + (size_t)l * 32;
        }
    }

    char* p = (char*)d_ws;
    auto alloc = [&](size_t bytes) -> void* {
        void* r = (void*)p;
        p += (bytes + 255) & ~(size_t)255;
        return r;
    };
    unsigned short* w2frag = (unsigned short*)alloc((size_t)4 * 2 * NCH * 512 * sizeof(unsigned short));
    uint4* emeta  = (uint4*)alloc((size_t)NE * sizeof(uint4));
    int* counts   = (int*)alloc((size_t)NN * sizeof(int));
    int* cursor   = (int*)alloc((size_t)NN * sizeof(int));
    int* rowst    = (int*)alloc((size_t)(NN + 1) * sizeof(int));
    unsigned* xA  = (unsigned*)alloc((size_t)NN * 16 * sizeof(unsigned));
    unsigned* xB  = (unsigned*)alloc((size_t)NN * 16 * sizeof(unsigned));
    float* ans    = (float*)alloc((size_t)NN * 32 * sizeof(float));
    float* outf   = (float*)d_out;

    hipMemsetAsync(counts, 0, (size_t)NN * sizeof(int), stream);

    histprep_kernel<<<1363, 256, 0, stream>>>(ei, counts, wp, feat, xA, w2frag);
    scan_kernel<<<1, 1024, 0, stream>>>(counts, rowst, cursor);
    fill_kernel<<<(NE + 255) / 256, 256, 0, stream>>>(ei, ej, attr, cursor, emeta);

    size_t wl = (size_t)2 * NCH * 512;
    fused_kernel<<<NN / 16, 1024, 0, stream>>>(xA, (unsigned short*)xB, emeta, rowst,
                                               w2frag + 0 * wl, fcB[0], ans, outf, 0);
    fused_kernel<<<NN / 16, 1024, 0, stream>>>(xB, (unsigned short*)xA, emeta, rowst,
                                               w2frag + 1 * wl, fcB[1], ans, outf, 1);
    fused_kernel<<<NN / 16, 1024, 0, stream>>>(xA, (unsigned short*)xB, emeta, rowst,
                                               w2frag + 2 * wl, fcB[2], ans, outf, 1);
    fused_kernel<<<NN / 16, 1024, 0, stream>>>(xB, (unsigned short*)xA, emeta, rowst,
                                               w2frag + 3 * wl, fcB[3], ans, outf, 2);
}

// Round 12
// 134.471 us; speedup vs baseline: 2.0328x; 1.1003x over previous
//
#include <hip/hip_runtime.h>
#include <hip/hip_bf16.h>

#define NN 20000
#define NE 320000
#define NCH 17        // 16 conv slots + 1 fc slot, K chunks of 32
#define SROWU 552     // per-node LDS row stride (ushorts): 544 + 8 pad (2-way banks)

typedef __attribute__((ext_vector_type(8))) short short8;
typedef __attribute__((ext_vector_type(4))) float f32x4;

__device__ __forceinline__ unsigned short f2bf(float v) {
    unsigned u = __float_as_uint(v);
    unsigned r = (u + 0x7fffu + ((u >> 16) & 1u)) >> 16;
    return (unsigned short)r;
}
__device__ __forceinline__ float bf2f(unsigned short s) {
    return __uint_as_float(((unsigned)s) << 16);
}

struct WPtrs { const float* cw[4]; const float* fw[4]; };

// x layout: per node 16 dwords; dword f = bf16(x[f]) | bf16(x[f+16])<<16

// ---- edge histogram
__global__ __launch_bounds__(256) void hist_kernel(const int* __restrict__ ei,
                                                   int* __restrict__ counts) {
    int e = blockIdx.x * 256 + threadIdx.x;      // 1250*256 == NE exactly
    atomicAdd(&counts[ei[e]], 1);
}

// ---- block 0: CSR scan; blocks 1-20: cast feat->interleaved bf16;
//      blocks 21-29: build W2frag (pre-swizzled MFMA B-fragments, 4 layers)
__global__ __launch_bounds__(1024) void scanprep_kernel(const int* __restrict__ counts,
                                                        int* __restrict__ rowst,
                                                        int* __restrict__ cursor,
                                                        WPtrs wp,
                                                        const float* __restrict__ feat,
                                                        unsigned* __restrict__ x0,
                                                        unsigned short* __restrict__ w2frag) {
    int b = blockIdx.x, t = threadIdx.x;
    if (b == 0) {
        __shared__ int s[1024];
        int base = t * 20;
        int v[20];
        int sum = 0;
#pragma unroll
        for (int i = 0; i < 20; i++) {
            int idx = base + i;
            v[i] = (idx < NN) ? counts[idx] : 0;
            sum += v[i];
        }
        s[t] = sum;
        __syncthreads();
#pragma unroll
        for (int off = 1; off < 1024; off <<= 1) {
            int add = (t >= off) ? s[t - off] : 0;
            __syncthreads();
            s[t] += add;
            __syncthreads();
        }
        int run = s[t] - sum;
        if (t == 0) rowst[0] = 0;
#pragma unroll
        for (int i = 0; i < 20; i++) {
            int idx = base + i;
            if (idx < NN) {
                cursor[idx] = run;
                rowst[idx + 1] = run + v[i];
            }
            run += v[i];
        }
    } else if (b <= 20) {
        int n = (b - 1) * 1024 + t;
        if (n < NN) {
            const float4* fr = (const float4*)(feat + (size_t)n * 32);
            float4 v0 = fr[0], v1 = fr[1], v2 = fr[2], v3 = fr[3];
            float4 v4 = fr[4], v5 = fr[5], v6 = fr[6], v7 = fr[7];
            float lo[16] = {v0.x, v0.y, v0.z, v0.w, v1.x, v1.y, v1.z, v1.w,
                            v2.x, v2.y, v2.z, v2.w, v3.x, v3.y, v3.z, v3.w};
            float hi[16] = {v4.x, v4.y, v4.z, v4.w, v5.x, v5.y, v5.z, v5.w,
                            v6.x, v6.y, v6.z, v6.w, v7.x, v7.y, v7.z, v7.w};
            unsigned o[16];
#pragma unroll
            for (int f = 0; f < 16; f++)
                o[f] = (unsigned)f2bf(lo[f]) | ((unsigned)f2bf(hi[f]) << 16);
            uint4* dst = (uint4*)(x0 + (size_t)n * 16);
#pragma unroll
            for (int q = 0; q < 4; q++) {
                uint4 w; w.x = o[q*4]; w.y = o[q*4+1]; w.z = o[q*4+2]; w.w = o[q*4+3];
                dst[q] = w;
            }
        }
    } else {
        int id2 = (b - 21) * 1024 + t;           // 4l * 2tile * 17c * 64lane = 8704
        if (id2 < 8704) {
            int lane = id2 & 63;
            int c = (id2 >> 6) % NCH;
            int lt = id2 / (NCH * 64);
            int l = lt >> 1, tt = lt & 1;
            int kb = (lane >> 4) * 8;
            int col = tt * 16 + (lane & 15);
            short8 o;
#pragma unroll
            for (int i = 0; i < 8; i++) {
                int k = c * 32 + kb + i;
                float v = (k < 512) ? wp.cw[l][(size_t)k * 32 + col]
                                    : wp.fw[l][(size_t)(k - 512) * 32 + col];
                o[i] = (short)f2bf(v);
            }
            *(short8*)(w2frag + (size_t)id2 * 8) = o;
        }
    }
}

// ---- CSR fill + edge basis precompute (layer-invariant)
// emeta[p] = { j | bb<<16, bf16x2 w(d0 lo, d1 hi), bf16x2 w(d4 lo, d5 hi), 0 }
__global__ __launch_bounds__(256) void fill_kernel(const int* __restrict__ ei,
                                                   const int* __restrict__ ej,
                                                   const float* __restrict__ attr,
                                                   int* __restrict__ cursor,
                                                   uint4* __restrict__ emeta) {
    int e = blockIdx.x * 256 + threadIdx.x;
    if (e >= NE) return;
    int i = ei[e], j = ej[e];
    int p = atomicAdd(&cursor[i], 1);
    float2 a = ((const float2*)attr)[e];
    float d0 = fminf(fmaxf(a.x, -1.f), 1.f);
    float d1 = fminf(fmaxf(a.y, -1.f), 1.f);
    float tx = (d0 + 1.f) * 1.5f;
    float ty = (d1 + 1.f) * 1.5f;
    int ix = min(2, max(0, (int)floorf(tx)));
    int iy = min(2, max(0, (int)floorf(ty)));
    float ux = tx - (float)ix;
    float uy = ty - (float)iy;
    float m = (i != j) ? 1.f : 0.f;   // centerIgnore
    uint4 mm;
    mm.x = (unsigned)j | ((unsigned)(ix * 4 + iy) << 16);
    mm.y = (unsigned)f2bf((1.f - ux) * (1.f - uy) * m)
         | ((unsigned)f2bf((1.f - ux) * uy * m) << 16);
    mm.z = (unsigned)f2bf(ux * (1.f - uy) * m)
         | ((unsigned)f2bf(ux * uy * m) << 16);
    mm.w = 0;
    emeta[p] = mm;
}

// ---- fused layer: 16 nodes/block, 1 wave/node.
// Phase A (scatter-by-MFMA): S_i = Phi_i^T . X_i, one mfma_16x16x32 per
// B-fragment per 32-edge chunk; D packed to bf16 in LDS (numerically identical
// to phase B's former read-time convert).
// Phase B: waves 0,1: ans = S . W2 -- per chunk ONE ds_read_b128 for A,
// one for W, one MFMA. +bias/residual/relu.
__global__ __launch_bounds__(1024, 8) void fused_kernel(const unsigned* __restrict__ xin,
                                                        unsigned short* __restrict__ xout,
                                                        const uint4* __restrict__ emeta,
                                                        const int* __restrict__ rowst,
                                                        const unsigned short* __restrict__ w2frag,
                                                        const float* __restrict__ bias,
                                                        float* __restrict__ ansbuf,
                                                        float* __restrict__ outf,
                                                        int mode) {
    __shared__ unsigned short su[16][SROWU];
    int tid = threadIdx.x;
    int wv = tid >> 6, lane = tid & 63;
    int fcol = lane & 15;              // A-row (slot) / B-col (feature) role
    int kg = lane >> 4;                // edge octet within chunk
    int node = blockIdx.x * 16 + wv;
    int r0 = rowst[node], r1 = rowst[node + 1];

    f32x4 acc0 = {0.f, 0.f, 0.f, 0.f};
    f32x4 acc1 = {0.f, 0.f, 0.f, 0.f};

    for (int qb = r0; qb < r1; qb += 32) {
        int last = r1 - 1;
        int qa = qb + kg * 8;
        uint4 mm[8];
#pragma unroll
        for (int i = 0; i < 8; i++) mm[i] = emeta[min(qa + i, last)];
        unsigned xv[8];
#pragma unroll
        for (int i = 0; i < 8; i++)
            xv[i] = xin[(size_t)(mm[i].x & 0xFFFF) * 16 + fcol];
        short8 av, bv0, bv1;
#pragma unroll
        for (int i = 0; i < 8; i++) {
            bv0[i] = (short)(unsigned short)(xv[i] & 0xFFFF);
            bv1[i] = (short)(unsigned short)(xv[i] >> 16);
            int d = fcol - (int)(mm[i].x >> 16);
            unsigned bits = (d == 0) ? (mm[i].y & 0xFFFFu)
                          : (d == 1) ? (mm[i].y >> 16)
                          : (d == 4) ? (mm[i].z & 0xFFFFu)
                          : (d == 5) ? (mm[i].z >> 16) : 0u;
            if (qa + i >= r1) bits = 0u;
            av[i] = (short)bits;
        }
        acc0 = __builtin_amdgcn_mfma_f32_16x16x32_bf16(av, bv0, acc0, 0, 0, 0);
        acc1 = __builtin_amdgcn_mfma_f32_16x16x32_bf16(av, bv1, acc1, 0, 0, 0);
    }
    // D -> LDS as bf16: lane holds D[slot = kg*4+r][fin = fcol and fcol+16]
#pragma unroll
    for (int r = 0; r < 4; r++) {
        int sr = kg * 4 + r;
        su[wv][sr * 32 + fcol]      = f2bf(acc0[r]);
        su[wv][sr * 32 + 16 + fcol] = f2bf(acc1[r]);
    }
    if (lane < 32) {   // fc slot: own features (bf16 bits direct from x)
        unsigned xv = xin[(size_t)node * 16 + (lane & 15)];
        su[wv][512 + lane] = (unsigned short)((lane < 16) ? (xv & 0xFFFF) : (xv >> 16));
    }
    __syncthreads();

    if (wv < 2) {
        int row = lane & 15;            // A-row = node within block
        int kb = (lane >> 4) * 8;
        const unsigned short* bp = w2frag + (size_t)wv * NCH * 512 + lane * 8;
        f32x4 acc = {0.f, 0.f, 0.f, 0.f};
#pragma unroll
        for (int c = 0; c < NCH; c++) {
            short8 av = *(const short8*)&su[row][c * 32 + kb];
            short8 bv = *(const short8*)(bp + (size_t)c * 512);
            acc = __builtin_amdgcn_mfma_f32_16x16x32_bf16(av, bv, acc, 0, 0, 0);
        }
        // D: col=lane&15 (feature), row=(lane>>4)*4+r (node within block)
        int fo = wv * 16 + (lane & 15);
        float bs = bias[fo];
        // interleaved xout position (ushort index within node): (fo&15)*2 + (fo>>4)
        int xpos = (fo & 15) * 2 + (fo >> 4);
#pragma unroll
        for (int r = 0; r < 4; r++) {
            int nd = blockIdx.x * 16 + (lane >> 4) * 4 + r;
            float val = acc[r] + bs;
            if (mode) val += ansbuf[(size_t)nd * 32 + fo];
            if (mode == 2) {
                outf[(size_t)nd * 32 + fo] = val * (1.f / 128.f);
            } else {
                ansbuf[(size_t)nd * 32 + fo] = val;
                xout[(size_t)nd * 32 + xpos] = f2bf(fmaxf(val, 0.f));
            }
        }
    }
}

extern "C" void kernel_launch(void* const* d_in, const int* in_sizes, int n_in,
                              void* d_out, int out_size, void* d_ws, size_t ws_size,
                              hipStream_t stream) {
    const float* feat = (const float*)d_in[0];
    const int* ei = (const int*)d_in[1];
    const int* ej = (const int*)d_in[2];
    const float* attr = (const float*)d_in[3];
    WPtrs wp;
    const float* fcB[4];
    if (n_in >= 16) {
        for (int l = 0; l < 4; l++) {
            wp.cw[l] = (const float*)d_in[4 + l];
            wp.fw[l] = (const float*)d_in[8 + l];
            fcB[l]   = (const float*)d_in[12 + l];
        }
    } else {
        const float* cb = (const float*)d_in[4];
        const float* fb = (const float*)d_in[5];
        const float* bb = (const float*)d_in[6];
        for (int l = 0; l < 4; l++) {
            wp.cw[l] = cb + (size_t)l * 16 * 32 * 32;
            wp.fw[l] = fb + (size_t)l * 32 * 32;
            fcB[l]   = bb + (size_t)l * 32;
        }
    }

    char* p = (char*)d_ws;
    auto alloc = [&](size_t bytes) -> void* {
        void* r = (void*)p;
        p += (bytes + 255) & ~(size_t)255;
        return r;
    };
    unsigned short* w2frag = (unsigned short*)alloc((size_t)4 * 2 * NCH * 512 * sizeof(unsigned short));
    uint4* emeta  = (uint4*)alloc((size_t)NE * sizeof(uint4));
    int* counts   = (int*)alloc((size_t)NN * sizeof(int));
    int* cursor   = (int*)alloc((size_t)NN * sizeof(int));
    int* rowst    = (int*)alloc((size_t)(NN + 1) * sizeof(int));
    unsigned* xA  = (unsigned*)alloc((size_t)NN * 16 * sizeof(unsigned));
    unsigned* xB  = (unsigned*)alloc((size_t)NN * 16 * sizeof(unsigned));
    float* ans    = (float*)alloc((size_t)NN * 32 * sizeof(float));
    float* outf   = (float*)d_out;

    hipMemsetAsync(counts, 0, (size_t)NN * sizeof(int), stream);

    hist_kernel<<<1250, 256, 0, stream>>>(ei, counts);
    scanprep_kernel<<<30, 1024, 0, stream>>>(counts, rowst, cursor, wp, feat, xA, w2frag);
    fill_kernel<<<(NE + 255) / 256, 256, 0, stream>>>(ei, ej, attr, cursor, emeta);

    size_t wl = (size_t)2 * NCH * 512;
    fused_kernel<<<NN / 16, 1024, 0, stream>>>(xA, (unsigned short*)xB, emeta, rowst,
                                               w2frag + 0 * wl, fcB[0], ans, outf, 0);
    fused_kernel<<<NN / 16, 1024, 0, stream>>>(xB, (unsigned short*)xA, emeta, rowst,
                                               w2frag + 1 * wl, fcB[1], ans, outf, 1);
    fused_kernel<<<NN / 16, 1024, 0, stream>>>(xA, (unsigned short*)xB, emeta, rowst,
                                               w2frag + 2 * wl, fcB[2], ans, outf, 1);
    fused_kernel<<<NN / 16, 1024, 0, stream>>>(xB, (unsigned short*)xA, emeta, rowst,
                                               w2frag + 3 * wl, fcB[3], ans, outf, 2);
}